// Round 2
// baseline (679.595 us; speedup 1.0000x reference)
//
#include <hip/hip_runtime.h>
#include <hip/hip_bf16.h>
#include <cstdint>
#include <math.h>

// Problem constants
#define S_LEN   2048
#define B_SZ    2
#define D_MODEL 2048
#define NH      16
#define NKV     4
#define HD      128
#define ROWS    (S_LEN * B_SZ)          // 4096
#define NQKV    3072                    // NH*HD + 2*NKV*HD
#define SCALE   0.08838834764831845f    // 1/sqrt(HD)

typedef __attribute__((ext_vector_type(8))) short short8;   // 8 bf16 = 4 VGPRs
typedef __attribute__((ext_vector_type(4))) short bf16x4;   // 4 bf16 = 2 VGPRs
typedef __attribute__((ext_vector_type(4))) float f32x4;    // MFMA acc

__device__ __forceinline__ short f2bf(float f) {
  union { float f; unsigned u; } v; v.f = f;
  unsigned r = v.u + 0x7fffu + ((v.u >> 16) & 1u);   // RNE
  return (short)(r >> 16);
}
__device__ __forceinline__ float bf2f(short x) {
  union { unsigned u; float f; } v;
  v.u = ((unsigned)(unsigned short)x) << 16;
  return v.f;
}

// async global->LDS 16B: dest is wave-uniform base + lane*16 (m104/m108 caveat)
__device__ __forceinline__ void async16(const short* g, short* l) {
  __builtin_amdgcn_global_load_lds(
      (const __attribute__((address_space(1))) void*)(uintptr_t)(const void*)g,
      (__attribute__((address_space(3))) void*)(uintptr_t)(void*)l,
      16, 0, 0);
}

// ---------------- fp32 -> bf16 elementwise (x) ----------------
__global__ void cvt_bf16_kernel(const float* __restrict__ src, short* __restrict__ dst, int n4) {
  int t = blockIdx.x * blockDim.x + threadIdx.x;
  if (t >= n4) return;
  float4 v = ((const float4*)src)[t];
  short4 o;
  o.x = f2bf(v.x); o.y = f2bf(v.y); o.z = f2bf(v.z); o.w = f2bf(v.w);
  *(short4*)(dst + (size_t)t * 4) = o;
}

// ------- fp32 [Kdim][Ndim] -> bf16 transposed [Ndim][Kdim] (weights) -------
__global__ void wtrans_kernel(const float* __restrict__ src, short* __restrict__ dst,
                              int Kdim, int Ndim) {
  __shared__ float tile[32][33];
  int n0 = blockIdx.x * 32, k0 = blockIdx.y * 32;
  for (int r = threadIdx.y; r < 32; r += 8)
    tile[r][threadIdx.x] = src[(size_t)(k0 + r) * Ndim + n0 + threadIdx.x];
  __syncthreads();
  for (int r = threadIdx.y; r < 32; r += 8)
    dst[(size_t)(n0 + r) * Kdim + k0 + threadIdx.x] = f2bf(tile[threadIdx.x][r]);
}

// ---------------- m97-style GEMM: C[M][N] = A[M][K] @ Bt[N][K]^T ----------------
#define BM 128
#define BN 128
#define BK 32

template<int BF16OUT>
__global__ __launch_bounds__(256) void gemm_bt_kernel(const short* __restrict__ A,
    const short* __restrict__ Bt, void* __restrict__ Cv, int M, int N, int K) {
  __shared__ alignas(16) short As[BM * BK];
  __shared__ alignas(16) short Bs[BN * BK];
  const int tid  = threadIdx.x;
  const int wave = tid >> 6;
  const int lane = tid & 63;
  const int quad = lane >> 4;
  const int lr   = lane & 15;
  const int m0 = blockIdx.y * BM;
  const int n0 = blockIdx.x * BN;
  const int wm = (wave >> 1) * 64;
  const int wn = (wave & 1) * 64;

  f32x4 acc[4][4];
#pragma unroll
  for (int i = 0; i < 4; i++)
#pragma unroll
    for (int j = 0; j < 4; j++) acc[i][j] = (f32x4){0.f, 0.f, 0.f, 0.f};

  // 128x32 tile = 512 chunks of 8 bf16; thread covers chunks tid and tid+256
  const int r0 = tid >> 2,          c0 = (tid & 3) * 8;
  const int r1 = (tid + 256) >> 2,  c1 = (tid & 3) * 8;  // (tid+256)&3 == tid&3

  for (int kt = 0; kt < K; kt += BK) {
    const short* ga = A  + (size_t)m0 * K + kt;
    const short* gb = Bt + (size_t)n0 * K + kt;
    async16(ga + (size_t)r0 * K + c0, As + wave * 512);
    async16(ga + (size_t)r1 * K + c1, As + 2048 + wave * 512);
    async16(gb + (size_t)r0 * K + c0, Bs + wave * 512);
    async16(gb + (size_t)r1 * K + c1, Bs + 2048 + wave * 512);
    __syncthreads();   // drains vmcnt for global_load_lds

    short8 a[4], b[4];
#pragma unroll
    for (int i = 0; i < 4; i++) a[i] = *(const short8*)(As + (wm + i * 16 + lr) * BK + quad * 8);
#pragma unroll
    for (int j = 0; j < 4; j++) b[j] = *(const short8*)(Bs + (wn + j * 16 + lr) * BK + quad * 8);
#pragma unroll
    for (int i = 0; i < 4; i++)
#pragma unroll
      for (int j = 0; j < 4; j++)
        acc[i][j] = __builtin_amdgcn_mfma_f32_16x16x32_bf16(a[i], b[j], acc[i][j], 0, 0, 0);
    __syncthreads();   // reads done before next stage overwrites
  }

#pragma unroll
  for (int i = 0; i < 4; i++) {
    const int row = m0 + wm + i * 16 + quad * 4;
#pragma unroll
    for (int j = 0; j < 4; j++) {
      const int col = n0 + wn + j * 16 + lr;
#pragma unroll
      for (int r = 0; r < 4; r++) {
        float v = acc[i][j][r];
        if (BF16OUT) ((short*)Cv)[(size_t)(row + r) * N + col] = f2bf(v);
        else         ((float*)Cv)[(size_t)(row + r) * N + col] = v;
      }
    }
  }
}

// ---------------- RoPE + scatter into attention layouts ----------------
// QKVb [4096][3072] bf16 -> Qb [B][NH][S][HD] (scaled), Kb [B][NKV][S][HD]
__global__ void rope_kernel(const short* __restrict__ QKVb, short* __restrict__ Qb,
                            short* __restrict__ Kb) {
  const int head = blockIdx.y;                              // 0..19: 0..15=Q, 16..19=K
  const int t = blockIdx.x * blockDim.x + threadIdx.x;      // 0..4096*64-1
  const int i = t & 63;
  const int row = t >> 6;                                   // s*B + b
  const int s = row >> 1;
  const int b = row & 1;
  float inv_freq = expf(-(float)i * (1.0f / 64.0f) * 9.210340371976184f); // theta^(-i/64)
  float ang = (float)s * inv_freq;
  float sn, cs;
  sincosf(ang, &sn, &cs);
  if (head < NH) {
    const short* p = QKVb + (size_t)row * NQKV + head * HD;
    float v1 = bf2f(p[i]), v2 = bf2f(p[i + 64]);
    short* q = Qb + ((size_t)(b * NH + head) * S_LEN + s) * HD;
    q[i]      = f2bf((v1 * cs - v2 * sn) * SCALE);
    q[i + 64] = f2bf((v2 * cs + v1 * sn) * SCALE);
  } else {
    const int kv = head - NH;
    const short* p = QKVb + (size_t)row * NQKV + NH * HD + kv * HD;
    float v1 = bf2f(p[i]), v2 = bf2f(p[i + 64]);
    short* k = Kb + ((size_t)(b * NKV + kv) * S_LEN + s) * HD;
    k[i]      = f2bf(v1 * cs - v2 * sn);
    k[i + 64] = f2bf(v2 * cs + v1 * sn);
  }
}

// ---------------- V transpose: QKVb V-cols -> Vtb [B][NKV][HD][S] ----------------
__global__ void vtrans_kernel(const short* __restrict__ QKVb, short* __restrict__ Vtb) {
  __shared__ short tile[32][33];
  const int bz = blockIdx.z;               // b*NKV + kv
  const int b  = bz >> 2;
  const int s0 = blockIdx.x * 32;
  const int d0 = blockIdx.y * 32;
  const int vcol = NH * HD + NKV * HD + (bz & 3) * HD;   // 2560 + kv*128
  for (int r = threadIdx.y; r < 32; r += 8)
    tile[r][threadIdx.x] = QKVb[(size_t)((s0 + r) * B_SZ + b) * NQKV + vcol + d0 + threadIdx.x];
  __syncthreads();
  for (int r = threadIdx.y; r < 32; r += 8)
    Vtb[((size_t)bz * HD + d0 + r) * S_LEN + s0 + threadIdx.x] = tile[threadIdx.x][r];
}

// ---------------- barrier-free transposed flash attention ----------------
// One wave owns one 16-row q-tile. Scores computed transposed: St = K*Q^T
// (A=K frag, B=Q frag, both direct global loads -> St[kv=quad*4+r][q=lr]).
// kv-step 16 + mfma 16x16x16: St C-layout IS the PV B-operand layout
// (k=quad*4+j, n=lr) -> zero P movement, zero LDS, zero barriers.
// O accumulated transposed: O^T[d][q] via A=V^T frag (direct from Vtb).
// Per-q stats (m,l,alpha) are per-lane scalars (q = lane&15).
// Block swizzle: blockIdx&7 = (b,kvh) stream (XCD L2 affinity, 1MB/stream),
// heavy q-groups first, sibling waves walk same K/V stream (L1 reuse).
template<bool DIAG>
__device__ __forceinline__ void attn_step(const short* __restrict__ Kp,
    const short* __restrict__ Vp, const short8 qf[4], int kv0, int quad, int lr,
    f32x4 o[8], float& m_i, float& l_i) {
  // K A-fragments: A[m=kv=lr][k=d], 16B each, direct from L2
  const short* kp = Kp + (size_t)(kv0 + lr) * HD + quad * 8;
  short8 kf0 = *(const short8*)(kp);
  short8 kf1 = *(const short8*)(kp + 32);
  short8 kf2 = *(const short8*)(kp + 64);
  short8 kf3 = *(const short8*)(kp + 96);
  // V^T A-fragments for PV: A[m=d=lr][k=kv=quad*4+j], 8B each
  bf16x4 vf[8];
#pragma unroll
  for (int dt = 0; dt < 8; ++dt)
    vf[dt] = *(const bf16x4*)(Vp + (size_t)(dt * 16 + lr) * S_LEN + kv0 + quad * 4);

  f32x4 sc = (f32x4){0.f, 0.f, 0.f, 0.f};
  sc = __builtin_amdgcn_mfma_f32_16x16x32_bf16(kf0, qf[0], sc, 0, 0, 0);
  sc = __builtin_amdgcn_mfma_f32_16x16x32_bf16(kf1, qf[1], sc, 0, 0, 0);
  sc = __builtin_amdgcn_mfma_f32_16x16x32_bf16(kf2, qf[2], sc, 0, 0, 0);
  sc = __builtin_amdgcn_mfma_f32_16x16x32_bf16(kf3, qf[3], sc, 0, 0, 0);

  if (DIAG) {   // only the diagonal tile needs masking: kv_local > q_local
#pragma unroll
    for (int r = 0; r < 4; ++r)
      if (quad * 4 + r > lr) sc[r] = -3.0e38f;
  }
  // column stats (per q = per lane, broadcast across quads via xor 16,32)
  float mb = fmaxf(fmaxf(sc[0], sc[1]), fmaxf(sc[2], sc[3]));
  mb = fmaxf(mb, __shfl_xor(mb, 16, 64));
  mb = fmaxf(mb, __shfl_xor(mb, 32, 64));
  float mnew = fmaxf(m_i, mb);

  float p0 = __expf(sc[0] - mnew), p1 = __expf(sc[1] - mnew);
  float p2 = __expf(sc[2] - mnew), p3 = __expf(sc[3] - mnew);
  float rs = (p0 + p1) + (p2 + p3);
  rs += __shfl_xor(rs, 16, 64);
  rs += __shfl_xor(rs, 32, 64);

  if (__any(mnew > m_i)) {           // skip rescale when no row max moved
    float alpha = __expf(m_i - mnew);
    l_i *= alpha;
#pragma unroll
    for (int n = 0; n < 8; ++n)
#pragma unroll
      for (int r = 0; r < 4; ++r) o[n][r] *= alpha;
    m_i = mnew;
  }
  l_i += rs;

  bf16x4 pb;
  pb[0] = f2bf(p0); pb[1] = f2bf(p1); pb[2] = f2bf(p2); pb[3] = f2bf(p3);
#pragma unroll
  for (int dt = 0; dt < 8; ++dt)
    o[dt] = __builtin_amdgcn_mfma_f32_16x16x16bf16_1k(vf[dt], pb, o[dt], 0, 0, 0);
}

__global__ __launch_bounds__(256) void attn_kernel(const short* __restrict__ Qb,
    const short* __restrict__ Kb, const short* __restrict__ Vtb, short* __restrict__ Ob) {
  const int tid = threadIdx.x, wave = tid >> 6, lane = tid & 63;
  const int quad = lane >> 4, lr = lane & 15;
  const int bid = blockIdx.x;
  const int sid  = bid & 7;           // (b,kvh) stream -> XCD affinity
  const int hsub = (bid >> 3) & 3;
  const int qg   = 31 - (bid >> 5);   // heavy q-groups dispatched first
  const int b = sid >> 2, kvh = sid & 3;
  const int h = kvh * 4 + hsub;
  const int qw = (qg * 4 + wave) * 16;

  const short* Qp = Qb  + ((size_t)(b * NH + h) * S_LEN + qw) * HD;
  const short* Kp = Kb  + (size_t)(b * NKV + kvh) * S_LEN * HD;
  const short* Vp = Vtb + (size_t)(b * NKV + kvh) * HD * S_LEN;

  // Q B-fragments (n=q=lr, k=d=quad*8+j within 32-chunk), loaded once
  short8 qf[4];
#pragma unroll
  for (int c = 0; c < 4; ++c)
    qf[c] = *(const short8*)(Qp + lr * HD + c * 32 + quad * 8);

  f32x4 o[8];
#pragma unroll
  for (int n = 0; n < 8; ++n) o[n] = (f32x4){0.f, 0.f, 0.f, 0.f};
  float m_i = -3.0e38f, l_i = 0.f;

  for (int kv0 = 0; kv0 < qw; kv0 += 16)
    attn_step<false>(Kp, Vp, qf, kv0, quad, lr, o, m_i, l_i);
  attn_step<true>(Kp, Vp, qf, qw, quad, lr, o, m_i, l_i);

  // epilogue: lane holds O^T[d = dt*16+quad*4+r][q = qw+lr]
  const float invl = 1.0f / l_i;
  short* op = Ob + ((size_t)(qw + lr) * B_SZ + b) * D_MODEL + h * HD + quad * 4;
#pragma unroll
  for (int dt = 0; dt < 8; ++dt) {
    short4 ov;
    ov.x = f2bf(o[dt][0] * invl);
    ov.y = f2bf(o[dt][1] * invl);
    ov.z = f2bf(o[dt][2] * invl);
    ov.w = f2bf(o[dt][3] * invl);
    *(short4*)(op + dt * 16) = ov;
  }
}

// ---------------- launch ----------------
extern "C" void kernel_launch(void* const* d_in, const int* in_sizes, int n_in,
                              void* d_out, int out_size, void* d_ws, size_t ws_size,
                              hipStream_t stream) {
  (void)in_sizes; (void)n_in; (void)out_size; (void)ws_size;
  const float* x  = (const float*)d_in[0];
  const float* Wq = (const float*)d_in[1];
  const float* Wk = (const float*)d_in[2];
  const float* Wv = (const float*)d_in[3];
  const float* Wo = (const float*)d_in[4];
  float* out = (float*)d_out;
  char* ws = (char*)d_ws;

  // region A [0, 29360128): Wqkv_t(12M)+xb(16M); later Qb(16M)+Kb(4M)+Vtb(4M)
  short* Wqkv_t = (short*)(ws);                    // [3072][2048]
  short* xb     = (short*)(ws + 12582912);         // [4096][2048]
  short* Qb     = (short*)(ws);                    // [2][16][2048][128]
  short* Kb     = (short*)(ws + 16777216);         // [2][4][2048][128]
  short* Vtb    = (short*)(ws + 20971520);         // [2][4][128][2048]
  // region B [29360128, 54525952): QKVb(24M); later Ob(16M)
  short* QKVb   = (short*)(ws + 29360128);         // [4096][3072]
  short* Ob     = (short*)(ws + 29360128);         // [4096][2048]
  // region C [54525952, 62914560): Wo_t(8M)
  short* Wo_t   = (short*)(ws + 54525952);         // [2048][2048]

  dim3 tblk(32, 8);

  // 1. x -> bf16
  cvt_bf16_kernel<<<(ROWS * D_MODEL / 4 + 255) / 256, 256, 0, stream>>>(x, xb, ROWS * D_MODEL / 4);
  // 2. weight transposes to B^T layout (bf16)
  wtrans_kernel<<<dim3(64, 64), tblk, 0, stream>>>(Wq, Wqkv_t,               2048, 2048);
  wtrans_kernel<<<dim3(16, 64), tblk, 0, stream>>>(Wk, Wqkv_t + 2048 * 2048, 2048,  512);
  wtrans_kernel<<<dim3(16, 64), tblk, 0, stream>>>(Wv, Wqkv_t + 2560 * 2048, 2048,  512);
  wtrans_kernel<<<dim3(64, 64), tblk, 0, stream>>>(Wo, Wo_t,                 2048, 2048);
  // 3. QKV projection (bf16 out)
  gemm_bt_kernel<1><<<dim3(NQKV / BN, ROWS / BM), 256, 0, stream>>>(xb, Wqkv_t, QKVb, ROWS, NQKV, D_MODEL);
  // 4. RoPE + scatter Q/K
  rope_kernel<<<dim3(1024, NH + NKV), 256, 0, stream>>>(QKVb, Qb, Kb);
  // 5. V transpose
  vtrans_kernel<<<dim3(S_LEN / 32, HD / 32, B_SZ * NKV), tblk, 0, stream>>>(QKVb, Vtb);
  // 6. causal flash attention (barrier-free, one wave per 16-row q-tile)
  attn_kernel<<<dim3(1024), 256, 0, stream>>>(Qb, Kb, Vtb, Ob);
  // 7. output projection (fp32 out)
  gemm_bt_kernel<0><<<dim3(D_MODEL / BN, ROWS / BM), 256, 0, stream>>>(Ob, Wo_t, out, ROWS, D_MODEL, D_MODEL);
}

// Round 3
// 350.178 us; speedup vs baseline: 1.9407x; 1.9407x over previous
//
#include <hip/hip_runtime.h>
#include <hip/hip_bf16.h>
#include <cstdint>
#include <math.h>

// Problem constants
#define S_LEN   2048
#define B_SZ    2
#define D_MODEL 2048
#define NH      16
#define NKV     4
#define HD      128
#define ROWS    (S_LEN * B_SZ)          // 4096
#define NQKV    3072                    // NH*HD + 2*NKV*HD
#define SCALE   0.08838834764831845f    // 1/sqrt(HD)

typedef __attribute__((ext_vector_type(8))) short short8;   // 8 bf16 = 4 VGPRs
typedef __attribute__((ext_vector_type(4))) float f32x4;    // MFMA acc

__device__ __forceinline__ short f2bf(float f) {
  union { float f; unsigned u; } v; v.f = f;
  unsigned r = v.u + 0x7fffu + ((v.u >> 16) & 1u);   // RNE
  return (short)(r >> 16);
}
__device__ __forceinline__ float bf2f(short x) {
  union { unsigned u; float f; } v;
  v.u = ((unsigned)(unsigned short)x) << 16;
  return v.f;
}

// async global->LDS 16B: dest is wave-uniform base + lane*16 (m104/m108 caveat)
__device__ __forceinline__ void async16(const short* g, short* l) {
  __builtin_amdgcn_global_load_lds(
      (const __attribute__((address_space(1))) void*)(uintptr_t)(const void*)g,
      (__attribute__((address_space(3))) void*)(uintptr_t)(void*)l,
      16, 0, 0);
}

// ---------------- fp32 -> bf16 elementwise (x) ----------------
__global__ void cvt_bf16_kernel(const float* __restrict__ src, short* __restrict__ dst, int n4) {
  int t = blockIdx.x * blockDim.x + threadIdx.x;
  if (t >= n4) return;
  float4 v = ((const float4*)src)[t];
  short4 o;
  o.x = f2bf(v.x); o.y = f2bf(v.y); o.z = f2bf(v.z); o.w = f2bf(v.w);
  *(short4*)(dst + (size_t)t * 4) = o;
}

// ------- fp32 [Kdim][Ndim] -> bf16 transposed [Ndim][Kdim] (weights) -------
__global__ void wtrans_kernel(const float* __restrict__ src, short* __restrict__ dst,
                              int Kdim, int Ndim) {
  __shared__ float tile[32][33];
  int n0 = blockIdx.x * 32, k0 = blockIdx.y * 32;
  for (int r = threadIdx.y; r < 32; r += 8)
    tile[r][threadIdx.x] = src[(size_t)(k0 + r) * Ndim + n0 + threadIdx.x];
  __syncthreads();
  for (int r = threadIdx.y; r < 32; r += 8)
    dst[(size_t)(n0 + r) * Kdim + k0 + threadIdx.x] = f2bf(tile[threadIdx.x][r]);
}

// ---------------- m97-style GEMM: C[M][N] = A[M][K] @ Bt[N][K]^T ----------------
#define BM 128
#define BN 128
#define BK 32

template<int BF16OUT>
__global__ __launch_bounds__(256) void gemm_bt_kernel(const short* __restrict__ A,
    const short* __restrict__ Bt, void* __restrict__ Cv, int M, int N, int K) {
  __shared__ alignas(16) short As[BM * BK];
  __shared__ alignas(16) short Bs[BN * BK];
  const int tid  = threadIdx.x;
  const int wave = tid >> 6;
  const int lane = tid & 63;
  const int quad = lane >> 4;
  const int lr   = lane & 15;
  const int m0 = blockIdx.y * BM;
  const int n0 = blockIdx.x * BN;
  const int wm = (wave >> 1) * 64;
  const int wn = (wave & 1) * 64;

  f32x4 acc[4][4];
#pragma unroll
  for (int i = 0; i < 4; i++)
#pragma unroll
    for (int j = 0; j < 4; j++) acc[i][j] = (f32x4){0.f, 0.f, 0.f, 0.f};

  const int r0 = tid >> 2,          c0 = (tid & 3) * 8;
  const int r1 = (tid + 256) >> 2,  c1 = (tid & 3) * 8;

  for (int kt = 0; kt < K; kt += BK) {
    const short* ga = A  + (size_t)m0 * K + kt;
    const short* gb = Bt + (size_t)n0 * K + kt;
    async16(ga + (size_t)r0 * K + c0, As + wave * 512);
    async16(ga + (size_t)r1 * K + c1, As + 2048 + wave * 512);
    async16(gb + (size_t)r0 * K + c0, Bs + wave * 512);
    async16(gb + (size_t)r1 * K + c1, Bs + 2048 + wave * 512);
    __syncthreads();

    short8 a[4], b[4];
#pragma unroll
    for (int i = 0; i < 4; i++) a[i] = *(const short8*)(As + (wm + i * 16 + lr) * BK + quad * 8);
#pragma unroll
    for (int j = 0; j < 4; j++) b[j] = *(const short8*)(Bs + (wn + j * 16 + lr) * BK + quad * 8);
#pragma unroll
    for (int i = 0; i < 4; i++)
#pragma unroll
      for (int j = 0; j < 4; j++)
        acc[i][j] = __builtin_amdgcn_mfma_f32_16x16x32_bf16(a[i], b[j], acc[i][j], 0, 0, 0);
    __syncthreads();
  }

#pragma unroll
  for (int i = 0; i < 4; i++) {
    const int row = m0 + wm + i * 16 + quad * 4;
#pragma unroll
    for (int j = 0; j < 4; j++) {
      const int col = n0 + wn + j * 16 + lr;
#pragma unroll
      for (int r = 0; r < 4; r++) {
        float v = acc[i][j][r];
        if (BF16OUT) ((short*)Cv)[(size_t)(row + r) * N + col] = f2bf(v);
        else         ((float*)Cv)[(size_t)(row + r) * N + col] = v;
      }
    }
  }
}

// ---------------- RoPE: Q -> Qb [B][NH][S][HD] (scaled); K -> packed frags ----
// Kpack entry: [stream][tile=s/16][c=d/32][lane=quad*16+(s&15)][j=d&7]
//   = K[s][c*32+quad*8+j]  (MFMA A-operand order for the QK^T matmul)
__global__ void rope_kernel(const short* __restrict__ QKVb, short* __restrict__ Qb,
                            short* __restrict__ Kpack) {
  const int head = blockIdx.y;                              // 0..19: 0..15=Q, 16..19=K
  const int t = blockIdx.x * blockDim.x + threadIdx.x;
  const int i = t & 63;
  const int row = t >> 6;                                   // s*B + b
  const int s = row >> 1;
  const int b = row & 1;
  float inv_freq = expf(-(float)i * (1.0f / 64.0f) * 9.210340371976184f); // theta^(-i/64)
  float ang = (float)s * inv_freq;
  float sn, cs;
  sincosf(ang, &sn, &cs);
  if (head < NH) {
    const short* p = QKVb + (size_t)row * NQKV + head * HD;
    float v1 = bf2f(p[i]), v2 = bf2f(p[i + 64]);
    short* q = Qb + ((size_t)(b * NH + head) * S_LEN + s) * HD;
    q[i]      = f2bf((v1 * cs - v2 * sn) * SCALE);
    q[i + 64] = f2bf((v2 * cs + v1 * sn) * SCALE);
  } else {
    const int kv = head - NH;
    const short* p = QKVb + (size_t)row * NQKV + NH * HD + kv * HD;
    float v1 = bf2f(p[i]), v2 = bf2f(p[i + 64]);
    float k1 = v1 * cs - v2 * sn;
    float k2 = v2 * cs + v1 * sn;
    short* kp = Kpack + (size_t)(b * NKV + kv) * S_LEN * HD;
    const int tile = s >> 4, lrr = s & 15;
    const int d1 = i, d2 = i + 64;
    kp[(size_t)((tile * 4 + (d1 >> 5)) * 64 + ((d1 >> 3) & 3) * 16 + lrr) * 8 + (d1 & 7)] = f2bf(k1);
    kp[(size_t)((tile * 4 + (d2 >> 5)) * 64 + ((d2 >> 3) & 3) * 16 + lrr) * 8 + (d2 & 7)] = f2bf(k2);
  }
}

// ---------------- V transpose: QKVb V-cols -> Vtb [B][NKV][HD][S] ----------------
__global__ void vtrans_kernel(const short* __restrict__ QKVb, short* __restrict__ Vtb) {
  __shared__ short tile[32][33];
  const int bz = blockIdx.z;               // b*NKV + kv
  const int b  = bz >> 2;
  const int s0 = blockIdx.x * 32;
  const int d0 = blockIdx.y * 32;
  const int vcol = NH * HD + NKV * HD + (bz & 3) * HD;
  for (int r = threadIdx.y; r < 32; r += 8)
    tile[r][threadIdx.x] = QKVb[(size_t)((s0 + r) * B_SZ + b) * NQKV + vcol + d0 + threadIdx.x];
  __syncthreads();
  for (int r = threadIdx.y; r < 32; r += 8)
    Vtb[((size_t)bz * HD + d0 + r) * S_LEN + s0 + threadIdx.x] = tile[threadIdx.x][r];
}

// -------- V^T fragment pack: Vtb [d][s] -> Vpack [chunk=s/32][dt=d/16][lane][8] --
// Vpack entry (chunk,dt,lane=quad*16+lr,j) = V^T[dt*16+lr][chunk*32+quad*8+j]
// -> PV A-operand is a fully-coalesced 16B/lane load.
__global__ void vpack_kernel(const short* __restrict__ Vtb, short* __restrict__ Vpack) {
  const int tid = threadIdx.x, wave = tid >> 6, lane = tid & 63;
  const int quad = lane >> 4, lr = lane & 15;
  const int chunk = blockIdx.x & 63, stream = blockIdx.x >> 6;
  const short* src = Vtb + (size_t)stream * HD * S_LEN;
  short* dst = Vpack + (size_t)stream * HD * S_LEN + chunk * 4096 + lane * 8;
#pragma unroll
  for (int k = 0; k < 2; ++k) {
    const int dt = wave + k * 4;
    short8 v = *(const short8*)(src + (size_t)(dt * 16 + lr) * S_LEN + chunk * 32 + quad * 8);
    *(short8*)(dst + dt * 512) = v;
  }
}

// ---------------- barrier-free transposed flash attention, 64-kv iters ----------
// One wave owns one 16-row q-tile. St = K*Q^T via packed K frags (coalesced 1KB
// loads). Batched softmax over 64 kv (2+2 shuffles). P round-trips through
// wave-private LDS (no barrier) to become the B-operand of a K=32 PV MFMA
// against packed V^T frags. Unconditional alpha rescale (no divergent branch).
#define PSP 72   // Ps row pitch in shorts (16B-aligned rows)

template<bool MASK>
__device__ __forceinline__ void attn_iter64(
    const short* __restrict__ Kpk, const short* __restrict__ Vpk,
    short* __restrict__ Psw, const short8 qf[4], int kv0, int nt, int qlim,
    int quad, int lr, f32x4 o[8], float& m_i, float& l_i)
{
  const int lane_off = (quad * 16 + lr) * 8;
  // --- K fragment loads (16B/lane, coalesced) ---
  short8 kf[4][4];
#pragma unroll
  for (int t = 0; t < 4; ++t)
    if (t < nt) {
      const short* kp = Kpk + (size_t)((kv0 >> 4) + t) * 2048 + lane_off;
#pragma unroll
      for (int c = 0; c < 4; ++c)
        kf[t][c] = *(const short8*)(kp + c * 512);
    }
  // --- QK^T (transposed scores: St[kv=quad*4+r][q=lr]) ---
  f32x4 sc[4];
#pragma unroll
  for (int t = 0; t < 4; ++t) {
    if (t < nt) {
      f32x4 s = (f32x4){0.f, 0.f, 0.f, 0.f};
#pragma unroll
      for (int c = 0; c < 4; ++c)
        s = __builtin_amdgcn_mfma_f32_16x16x32_bf16(kf[t][c], qf[c], s, 0, 0, 0);
      sc[t] = s;
    } else {
      sc[t] = (f32x4){-3.0e38f, -3.0e38f, -3.0e38f, -3.0e38f};
    }
  }
  // --- V fragment loads (issued before softmax VALU for overlap) ---
  const bool c1v = !MASK || (nt > 2);
  short8 vf0[8], vf1[8];
  const short* vp = Vpk + (size_t)(kv0 >> 5) * 4096 + lane_off;
#pragma unroll
  for (int dt = 0; dt < 8; ++dt) vf0[dt] = *(const short8*)(vp + dt * 512);
  if (c1v) {
#pragma unroll
    for (int dt = 0; dt < 8; ++dt) vf1[dt] = *(const short8*)(vp + 4096 + dt * 512);
  }
  // --- causal mask (tail only) ---
  if (MASK) {
#pragma unroll
    for (int t = 0; t < 4; ++t)
#pragma unroll
      for (int r = 0; r < 4; ++r)
        if (kv0 + t * 16 + quad * 4 + r > qlim) sc[t][r] = -3.0e38f;
  }
  // --- batched online softmax (per-lane column stats, q = lr) ---
  float mb = -3.0e38f;
#pragma unroll
  for (int t = 0; t < 4; ++t)
#pragma unroll
    for (int r = 0; r < 4; ++r) mb = fmaxf(mb, sc[t][r]);
  mb = fmaxf(mb, __shfl_xor(mb, 16, 64));
  mb = fmaxf(mb, __shfl_xor(mb, 32, 64));
  const float mnew = fmaxf(m_i, mb);
  const float alpha = __expf(m_i - mnew);
  m_i = mnew;
  float rs = 0.f;
#pragma unroll
  for (int t = 0; t < 4; ++t) {
    short4 pw;
    float p0 = __expf(sc[t][0] - mnew);
    float p1 = __expf(sc[t][1] - mnew);
    float p2 = __expf(sc[t][2] - mnew);
    float p3 = __expf(sc[t][3] - mnew);
    rs += (p0 + p1) + (p2 + p3);
    pw.x = f2bf(p0); pw.y = f2bf(p1); pw.z = f2bf(p2); pw.w = f2bf(p3);
    *(short4*)(Psw + lr * PSP + t * 16 + quad * 4) = pw;   // P^T as [q][kv]
  }
  rs += __shfl_xor(rs, 16, 64);
  rs += __shfl_xor(rs, 32, 64);
  l_i = l_i * alpha + rs;
#pragma unroll
  for (int n = 0; n < 8; ++n)
#pragma unroll
    for (int r = 0; r < 4; ++r) o[n][r] *= alpha;
  // --- P B-frags (K=32) from wave-private LDS; PV ---
  short8 pb0 = *(const short8*)(Psw + lr * PSP + quad * 8);
#pragma unroll
  for (int dt = 0; dt < 8; ++dt)
    o[dt] = __builtin_amdgcn_mfma_f32_16x16x32_bf16(vf0[dt], pb0, o[dt], 0, 0, 0);
  if (c1v) {
    short8 pb1 = *(const short8*)(Psw + lr * PSP + 32 + quad * 8);
#pragma unroll
    for (int dt = 0; dt < 8; ++dt)
      o[dt] = __builtin_amdgcn_mfma_f32_16x16x32_bf16(vf1[dt], pb1, o[dt], 0, 0, 0);
  }
}

__global__ __launch_bounds__(256) void attn_kernel(const short* __restrict__ Qb,
    const short* __restrict__ Kpack, const short* __restrict__ Vpack,
    short* __restrict__ Ob) {
  __shared__ alignas(16) short Ps[4][16 * PSP];
  const int tid = threadIdx.x, wave = tid >> 6, lane = tid & 63;
  const int quad = lane >> 4, lr = lane & 15;
  const int bid = blockIdx.x;
  const int sid  = bid & 7;           // (b,kvh) stream -> XCD L2 affinity
  const int hsub = (bid >> 3) & 3;
  const int qg   = 31 - (bid >> 5);   // heavy q-groups dispatched first
  const int b = sid >> 2, kvh = sid & 3;
  const int h = kvh * 4 + hsub;
  const int qw = (qg * 4 + wave) * 16;

  const short* Qp  = Qb    + ((size_t)(b * NH + h) * S_LEN + qw) * HD;
  const short* Kpk = Kpack + (size_t)(b * NKV + kvh) * S_LEN * HD;
  const short* Vpk = Vpack + (size_t)(b * NKV + kvh) * HD * S_LEN;
  short* Psw = &Ps[wave][0];

  // Q B-fragments (n=q=lr, k=d), loaded once
  short8 qf[4];
#pragma unroll
  for (int c = 0; c < 4; ++c)
    qf[c] = *(const short8*)(Qp + lr * HD + c * 32 + quad * 8);

  f32x4 o[8];
#pragma unroll
  for (int n = 0; n < 8; ++n) o[n] = (f32x4){0.f, 0.f, 0.f, 0.f};
  float m_i = -3.0e38f, l_i = 0.f;

  const int full = qw >> 6;
  const int qlim = qw + lr;
  for (int it = 0; it < full; ++it)
    attn_iter64<false>(Kpk, Vpk, Psw, qf, it * 64, 4, qlim, quad, lr, o, m_i, l_i);
  attn_iter64<true>(Kpk, Vpk, Psw, qf, full * 64, ((qw & 63) >> 4) + 1, qlim,
                    quad, lr, o, m_i, l_i);

  // epilogue: lane holds O^T[d = dt*16+quad*4+r][q = qw+lr]
  const float invl = 1.0f / l_i;
  short* op = Ob + ((size_t)(qw + lr) * B_SZ + b) * D_MODEL + h * HD + quad * 4;
#pragma unroll
  for (int dt = 0; dt < 8; ++dt) {
    short4 ov;
    ov.x = f2bf(o[dt][0] * invl);
    ov.y = f2bf(o[dt][1] * invl);
    ov.z = f2bf(o[dt][2] * invl);
    ov.w = f2bf(o[dt][3] * invl);
    *(short4*)(op + dt * 16) = ov;
  }
}

// ---------------- launch ----------------
extern "C" void kernel_launch(void* const* d_in, const int* in_sizes, int n_in,
                              void* d_out, int out_size, void* d_ws, size_t ws_size,
                              hipStream_t stream) {
  (void)in_sizes; (void)n_in; (void)out_size; (void)ws_size;
  const float* x  = (const float*)d_in[0];
  const float* Wq = (const float*)d_in[1];
  const float* Wk = (const float*)d_in[2];
  const float* Wv = (const float*)d_in[3];
  const float* Wo = (const float*)d_in[4];
  float* out = (float*)d_out;
  char* ws = (char*)d_ws;

  // region A [0, 29360128): Wqkv_t(12M)+xb(16M); later Qb(16M)+Kpack(4M)+Vtb(4M)+Vpack(4M)
  short* Wqkv_t = (short*)(ws);                    // [3072][2048]
  short* xb     = (short*)(ws + 12582912);         // [4096][2048]
  short* Qb     = (short*)(ws);                    // [2][16][2048][128]
  short* Kpack  = (short*)(ws + 16777216);         // packed K frags, 4MB
  short* Vtb    = (short*)(ws + 20971520);         // [2][4][128][2048]
  short* Vpack  = (short*)(ws + 25165824);         // packed V^T frags, 4MB
  // region B [29360128, 54525952): QKVb(24M); later Ob(16M)
  short* QKVb   = (short*)(ws + 29360128);         // [4096][3072]
  short* Ob     = (short*)(ws + 29360128);         // [4096][2048]
  // region C [54525952, 62914560): Wo_t(8M)
  short* Wo_t   = (short*)(ws + 54525952);         // [2048][2048]

  dim3 tblk(32, 8);

  // 1. x -> bf16
  cvt_bf16_kernel<<<(ROWS * D_MODEL / 4 + 255) / 256, 256, 0, stream>>>(x, xb, ROWS * D_MODEL / 4);
  // 2. weight transposes to B^T layout (bf16)
  wtrans_kernel<<<dim3(64, 64), tblk, 0, stream>>>(Wq, Wqkv_t,               2048, 2048);
  wtrans_kernel<<<dim3(16, 64), tblk, 0, stream>>>(Wk, Wqkv_t + 2048 * 2048, 2048,  512);
  wtrans_kernel<<<dim3(16, 64), tblk, 0, stream>>>(Wv, Wqkv_t + 2560 * 2048, 2048,  512);
  wtrans_kernel<<<dim3(64, 64), tblk, 0, stream>>>(Wo, Wo_t,                 2048, 2048);
  // 3. QKV projection (bf16 out)
  gemm_bt_kernel<1><<<dim3(NQKV / BN, ROWS / BM), 256, 0, stream>>>(xb, Wqkv_t, QKVb, ROWS, NQKV, D_MODEL);
  // 4. RoPE: Q -> Qb, K -> packed frags
  rope_kernel<<<dim3(1024, NH + NKV), 256, 0, stream>>>(QKVb, Qb, Kpack);
  // 5. V transpose + fragment pack
  vtrans_kernel<<<dim3(S_LEN / 32, HD / 32, B_SZ * NKV), tblk, 0, stream>>>(QKVb, Vtb);
  vpack_kernel<<<dim3(512), 256, 0, stream>>>(Vtb, Vpack);
  // 6. causal flash attention (barrier-free, packed frags, 64-kv iters)
  attn_kernel<<<dim3(1024), 256, 0, stream>>>(Qb, Kpack, Vpack, Ob);
  // 7. output projection (fp32 out)
  gemm_bt_kernel<0><<<dim3(D_MODEL / BN, ROWS / BM), 256, 0, stream>>>(Ob, Wo_t, out, ROWS, D_MODEL, D_MODEL);
}